// Round 3
// baseline (783.161 us; speedup 1.0000x reference)
//
#include <hip/hip_runtime.h>

#define IMG_H 512
#define IMG_W 512
#define WOUT  128          // output cols per block
#define WV    144          // WOUT + 16 halo cols (valid data cols per row)
#define SP    296          // sin_ slot pitch (floats); 1184B, 2-slot stride = 16-bank shift
#define SB    148          // b2 plane offset within a slot (floats), 592B (16B aligned)
#define NRING 24           // circular input row slots (16 halo + 8 step rows)
#define RS    8            // rows per step
#define NSTEP 8            // steps per block (64-row strip)
#define SVP   152          // sv_ row pitch (floats); 608B, 2-row stride = 16-bank shift
#define PS    (RS * SVP)   // sv_ plane stride (floats) = 1216
#define C1F   1.0e-4f
#define C2F   9.0e-4f

// ---------------------------------------------------------------------------
// prep: extract exact separable 1D weights from the 2D filters.
// ws layout (floats): [0..4]=w5, [8..18]=w11, [32..48]=w17
// ---------------------------------------------------------------------------
__global__ void prep_weights_kernel(const float* __restrict__ g0,
                                    const float* __restrict__ g1,
                                    const float* __restrict__ g2,
                                    float* __restrict__ ws) {
  if (blockIdx.x == 0 && threadIdx.x == 0) {
    const float* gs[3] = {g0, g1, g2};
    const int ks[3]  = {5, 11, 17};
    const int off[3] = {0, 8, 32};
    for (int s = 0; s < 3; ++s) {
      const float* g = gs[s];
      int k = ks[s], h = k / 2;
      double rs = 1.0 / sqrt((double)g[h * k + h]);
      for (int j = 0; j < k; ++j)
        ws[off[s] + j] = (float)((double)g[h * k + j] * rs);
    }
  }
}

__device__ __forceinline__ float to_sgpr(float x) {
  int i = __builtin_amdgcn_readfirstlane(__builtin_bit_cast(int, x));
  return __builtin_bit_cast(float, i);
}

__device__ __forceinline__ int mod24(int x) {  // valid for 0 <= x < ~1500
  return x - 24 * ((x * 2731) >> 16);
}

// generic staging (prologue): rows gr0..gr0+NROWS-1 into the ring.
template<int NROWS>
__device__ __forceinline__ void stage_rows(const float* __restrict__ p1,
                                           const float* __restrict__ p2,
                                           float* __restrict__ sin_,
                                           int gr0, int x0, int tid) {
  constexpr int NT = NROWS * WV;
  for (int idx = tid; idx < NT; idx += 256) {
    int rr = ((idx >> 4) * 7282) >> 16;   // idx / 144
    int cc = idx - rr * WV;
    int gr = gr0 + rr;
    int gc = x0 - 8 + cc;
    float v1 = 0.f, v2 = 0.f;
    if ((unsigned)gr < (unsigned)IMG_H && (unsigned)gc < (unsigned)IMG_W) {
      int o = gr * IMG_W + gc;
      v1 = p1[o];
      v2 = p2[o];
    }
    int slot = mod24(gr + 56);            // == (gr+8) mod 24, gr >= -8
    float* p = sin_ + slot * SP + cc;
    p[0]  = v1;
    p[SB] = v2;
  }
}

// split staging for RS=8 rows (NT=1152, 5 part-iterations of 256):
// issue global loads EARLY (before H5 compute), write LDS LATE (after), so
// HBM latency hides under the H5 VALU work (T14 async-stage split).
struct Stage8 { float v1[5], v2[5]; };

__device__ __forceinline__ void stage8_load(const float* __restrict__ p1,
                                            const float* __restrict__ p2,
                                            int gr0, int x0, int tid,
                                            Stage8& st) {
  constexpr int NT = RS * WV;             // 1152
  #pragma unroll
  for (int it = 0; it < 5; ++it) {
    int idx = tid + it * 256;
    float v1 = 0.f, v2 = 0.f;
    if (idx < NT) {
      int rr = ((idx >> 4) * 7282) >> 16;
      int cc = idx - rr * WV;
      int gr = gr0 + rr;
      int gc = x0 - 8 + cc;
      if ((unsigned)gr < (unsigned)IMG_H && (unsigned)gc < (unsigned)IMG_W) {
        int o = gr * IMG_W + gc;
        v1 = p1[o];
        v2 = p2[o];
      }
    }
    st.v1[it] = v1;
    st.v2[it] = v2;
  }
}

__device__ __forceinline__ void stage8_write(float* __restrict__ sin_,
                                             int gr0, int tid,
                                             const Stage8& st) {
  constexpr int NT = RS * WV;
  #pragma unroll
  for (int it = 0; it < 5; ++it) {
    int idx = tid + it * 256;
    if (idx < NT) {
      int rr = ((idx >> 4) * 7282) >> 16;
      int cc = idx - rr * WV;
      int gr = gr0 + rr;
      int slot = mod24(gr + 56);
      float* p = sin_ + slot * SP + cc;
      p[0]  = st.v1[it];
      p[SB] = st.v2[it];
    }
  }
}

// vertical pass, 2-row register blocking, 4 planes.
// SSIM algebra only needs sigma1_sq+sigma2_sq (both variances are >=0, so the
// reference's abs() is a no-op up to ~1e-7 rounding) -> convolve
// {x, y, x^2+y^2, x*y} instead of {x, y, x^2, y^2, x*y}: -20% acc FMAs,
// -20% sv_ writes, -20% H reads.
template<int K>
__device__ __forceinline__ void v_col2(const float (&wk)[K],
                                       const float* __restrict__ sin_,
                                       float* __restrict__ sv_,
                                       int yc, int t) {
  constexpr int HK = K / 2;
  const int rp = (t * 1821) >> 16;        // t / 36, valid t < 288
  const int cc = t - rp * 36;
  const int r0 = rp * 2;
  const int cb = 4 * cc;

  float acc[4][2][4];
  #pragma unroll
  for (int d = 0; d < 4; ++d)
    #pragma unroll
    for (int r = 0; r < 2; ++r)
      #pragma unroll
      for (int j = 0; j < 4; ++j) acc[d][r][j] = 0.f;

  // slot of first tap row (row yc+r0-HK): ((yc+r0-HK)+8) mod 24
  const int us = mod24(yc + r0 + (8 - HK));
  const float* pA = sin_ + us * SP + cb;
  const float* pB = pA - NRING * SP;

  #pragma unroll
  for (int i = 0; i <= K; ++i) {
    const float* row = (us + i < NRING) ? pA : pB;
    float4 A  = *(const float4*)(row + i * SP);
    float4 Bv = *(const float4*)(row + i * SP + SB);
    float x[4] = {A.x, A.y, A.z, A.w};
    float y[4] = {Bv.x, Bv.y, Bv.z, Bv.w};
    float pp[4], qq[4];
    #pragma unroll
    for (int j = 0; j < 4; ++j) {
      pp[j] = fmaf(x[j], x[j], y[j] * y[j]);   // x^2 + y^2
      qq[j] = x[j] * y[j];                     // x * y
    }
    if (i < K) {            // contributes to row r0 with weight wk[i]
      const float w = wk[i];
      #pragma unroll
      for (int j = 0; j < 4; ++j) {
        acc[0][0][j] = fmaf(w, x[j],  acc[0][0][j]);
        acc[1][0][j] = fmaf(w, y[j],  acc[1][0][j]);
        acc[2][0][j] = fmaf(w, pp[j], acc[2][0][j]);
        acc[3][0][j] = fmaf(w, qq[j], acc[3][0][j]);
      }
    }
    if (i > 0) {            // contributes to row r0+1 with weight wk[i-1]
      const float w = wk[i - 1];
      #pragma unroll
      for (int j = 0; j < 4; ++j) {
        acc[0][1][j] = fmaf(w, x[j],  acc[0][1][j]);
        acc[1][1][j] = fmaf(w, y[j],  acc[1][1][j]);
        acc[2][1][j] = fmaf(w, pp[j], acc[2][1][j]);
        acc[3][1][j] = fmaf(w, qq[j], acc[3][1][j]);
      }
    }
  }

  #pragma unroll
  for (int d = 0; d < 4; ++d) {
    #pragma unroll
    for (int r = 0; r < 2; ++r) {
      float* vb = sv_ + d * PS + (r0 + r) * SVP + cb;
      *(float4*)vb = make_float4(acc[d][r][0], acc[d][r][1],
                                 acc[d][r][2], acc[d][r][3]);
    }
  }
}

// horizontal pass + partial ssim for (row rr, 4-col group g), 4 planes.
template<int K>
__device__ __forceinline__ void h_col(const float (&wk)[K],
                                      const float* __restrict__ sv_,
                                      int rr, int g, float (&accs)[4]) {
  constexpr int OFF = 8 - K / 2;
  float conv[4][4];
  #pragma unroll
  for (int d = 0; d < 4; ++d) {
    const float* vb = sv_ + d * PS + rr * SVP + 4 * g;
    float win[20];
    if constexpr (K == 5) {
      #pragma unroll
      for (int q = 1; q < 4; ++q) {
        float4 t4 = *(const float4*)(vb + 4 * q);
        win[4*q+0] = t4.x; win[4*q+1] = t4.y; win[4*q+2] = t4.z; win[4*q+3] = t4.w;
      }
    } else {
      #pragma unroll
      for (int q = 0; q < 5; ++q) {
        float4 t4 = *(const float4*)(vb + 4 * q);
        win[4*q+0] = t4.x; win[4*q+1] = t4.y; win[4*q+2] = t4.z; win[4*q+3] = t4.w;
      }
    }
    #pragma unroll
    for (int j = 0; j < 4; ++j) {
      float s = 0.f;
      #pragma unroll
      for (int t = 0; t < K; ++t) s = fmaf(wk[t], win[j + t + OFF], s);
      conv[d][j] = s;
    }
  }
  #pragma unroll
  for (int j = 0; j < 4; ++j) {
    float mu1 = conv[0][j], mu2 = conv[1][j];
    float P = conv[2][j], Q = conv[3][j];
    float mu11 = mu1 * mu1, mu22 = mu2 * mu2, mu12 = mu1 * mu2;
    float sg12 = Q - mu12;                 // sigma12
    float sgS  = P - mu11 - mu22;          // sigma1_sq + sigma2_sq
    float num  = fmaf(2.f, mu12, C1F) * fmaf(2.f, sg12, C2F);
    float den  = (mu11 + mu22 + C1F) * (sgS + C2F);
    float ssim = __fdividef(num, den);
    accs[j] += fminf(1.f, fmaxf(-1.f, ssim));
  }
}

// ---------------------------------------------------------------------------
// main fused kernel: grid = 96 images * 8 row-strips * 4 col-blocks = 3072
// block = 256 threads; LDS = 28416 (input ring) + 19456 (4 V planes) = 47872 B
//   -> 3 blocks/CU (12 waves/CU); 6 barriers per 8-row step; staging for the
//   next step overlaps the H5 epoch (loads early / LDS-write late).
// ---------------------------------------------------------------------------
__global__ __launch_bounds__(256, 3)
void mssim_kernel(const float* __restrict__ b1, const float* __restrict__ b2,
                  const float* __restrict__ ws, float* __restrict__ out) {
  __shared__ __attribute__((aligned(16))) float sin_[NRING * SP];
  __shared__ __attribute__((aligned(16))) float sv_[4 * PS];

  const int tid = threadIdx.x;
  const int bid = blockIdx.x;
  const int img = bid >> 5;
  const int rem = bid & 31;
  const int y0  = (rem >> 2) * (RS * NSTEP);
  const int x0  = (rem & 3) * WOUT;
  const float* p1 = b1 + img * (IMG_H * IMG_W);
  const float* p2 = b2 + img * (IMG_H * IMG_W);
  float*       po = out + img * (IMG_H * IMG_W);

  // weights -> SGPRs (single scalar operand per FMA)
  float w17[17], w11[11], w5[5];
  #pragma unroll
  for (int i = 0; i < 17; ++i) w17[i] = to_sgpr(ws[32 + i]);
  #pragma unroll
  for (int i = 0; i < 11; ++i) w11[i] = to_sgpr(ws[8 + i]);
  #pragma unroll
  for (int i = 0; i < 5;  ++i) w5[i]  = to_sgpr(ws[i]);

  // prologue: stage rows y0-8 .. y0+15 (all rows step 0's V17 needs)
  stage_rows<24>(p1, p2, sin_, y0 - 8, x0, tid);

  const int hr = tid >> 5;            // H row within step (0..7)
  const int hg = tid & 31;            // H 4-col group (0..31)
  const bool vact = tid < 144;        // V tasks: 4 row-pairs x 36 col groups

  #pragma unroll 1
  for (int step = 0; step < NSTEP; ++step) {
    const int yc = y0 + step * RS;
    __syncthreads();                  // staged rows (prev H5 epoch) visible

    float accs[4] = {0.f, 0.f, 0.f, 0.f};

    if (vact) v_col2<17>(w17, sin_, sv_, yc, tid);
    __syncthreads();
    h_col<17>(w17, sv_, hr, hg, accs);
    __syncthreads();

    if (vact) v_col2<11>(w11, sin_, sv_, yc, tid);
    __syncthreads();
    h_col<11>(w11, sv_, hr, hg, accs);
    __syncthreads();

    if (vact) v_col2<5>(w5, sin_, sv_, yc, tid);
    __syncthreads();

    // H5 epoch: issue next-step global loads, compute H5, then LDS-write.
    // The staged slots' previous contents (rows yc-8..yc-1) were last read
    // by V17 of THIS step -- separated by >=1 barrier. Next reader (V17 of
    // step+1) is after the top-of-loop barrier.
    Stage8 st;
    const bool do_stage = (step < NSTEP - 1);
    if (do_stage) stage8_load(p1, p2, yc + 16, x0, tid, st);
    h_col<5>(w5, sv_, hr, hg, accs);
    if (do_stage) stage8_write(sin_, yc + 16, tid, st);

    // out = 1 - ((sum_s (1-(clip_s+1)/2))/3 + 1)/2  ==  0.25 + sum(clip_s)/12
    float4 o = make_float4(0.25f + accs[0] * (1.f / 12.f),
                           0.25f + accs[1] * (1.f / 12.f),
                           0.25f + accs[2] * (1.f / 12.f),
                           0.25f + accs[3] * (1.f / 12.f));
    *(float4*)(po + (yc + hr) * IMG_W + x0 + 4 * hg) = o;
  }
}

extern "C" void kernel_launch(void* const* d_in, const int* in_sizes, int n_in,
                              void* d_out, int out_size, void* d_ws, size_t ws_size,
                              hipStream_t stream) {
  const float* b1 = (const float*)d_in[0];
  const float* b2 = (const float*)d_in[1];
  const float* g0 = (const float*)d_in[2];
  const float* g1 = (const float*)d_in[3];
  const float* g2 = (const float*)d_in[4];
  float* ws  = (float*)d_ws;
  float* out = (float*)d_out;

  prep_weights_kernel<<<1, 64, 0, stream>>>(g0, g1, g2, ws);
  mssim_kernel<<<3072, 256, 0, stream>>>(b1, b2, ws, out);
}

// Round 4
// 536.864 us; speedup vs baseline: 1.4588x; 1.4588x over previous
//
#include <hip/hip_runtime.h>

#define IMG_H 512
#define IMG_W 512
#define WOUT  128          // output cols per block
#define WV    144          // WOUT + 16 halo cols (valid data cols per row)
#define SP    296          // sin_ slot pitch (floats); 1184B, 2-slot stride = 16-bank shift
#define SB    148          // b2 plane offset within a slot (floats), 592B (16B aligned)
#define NRING 24           // circular input row slots (16 halo + 8 step rows)
#define RS    8            // rows per step
#define NSTEP 8            // steps per block (64-row strip)
#define SVP   152          // sv_ row pitch (floats); 608B, 2-row stride = 16-bank shift
#define PS    (RS * SVP)   // sv_ plane stride (floats) = 1216
#define C1F   1.0e-4f
#define C2F   9.0e-4f

// ---------------------------------------------------------------------------
// prep: extract exact separable 1D weights from the 2D filters.
// ws layout (floats): [0..4]=w5, [8..18]=w11, [32..48]=w17
// ---------------------------------------------------------------------------
__global__ void prep_weights_kernel(const float* __restrict__ g0,
                                    const float* __restrict__ g1,
                                    const float* __restrict__ g2,
                                    float* __restrict__ ws) {
  if (blockIdx.x == 0 && threadIdx.x == 0) {
    const float* gs[3] = {g0, g1, g2};
    const int ks[3]  = {5, 11, 17};
    const int off[3] = {0, 8, 32};
    for (int s = 0; s < 3; ++s) {
      const float* g = gs[s];
      int k = ks[s], h = k / 2;
      double rs = 1.0 / sqrt((double)g[h * k + h]);
      for (int j = 0; j < k; ++j)
        ws[off[s] + j] = (float)((double)g[h * k + j] * rs);
    }
  }
}

__device__ __forceinline__ float to_sgpr(float x) {
  int i = __builtin_amdgcn_readfirstlane(__builtin_bit_cast(int, x));
  return __builtin_bit_cast(float, i);
}

__device__ __forceinline__ int mod24(int x) {  // valid for 0 <= x < ~1500
  return x - 24 * ((x * 2731) >> 16);
}

// staging, float4 granularity: rows gr0..gr0+NROWS-1 into the ring.
// NROWS*36 f4 tasks; task t -> row t/36, 4-col group t%36. Both the global
// loads (dwordx4, 16B-aligned since x0%128==0) and the LDS writes (b128) are
// vectorized. 512-col boundary is 4-col aligned -> per-group OOB guard only.
// Magic t/36 valid for t < 864 (covers NROWS<=24).
template<int NROWS>
__device__ __forceinline__ void stage_rows(const float* __restrict__ p1,
                                           const float* __restrict__ p2,
                                           float* __restrict__ sin_,
                                           int gr0, int x0, int tid) {
  constexpr int NT = NROWS * 36;
  for (int t = tid; t < NT; t += 256) {
    int rr = (t * 1821) >> 16;            // t / 36
    int c4 = t - rr * 36;
    int gr = gr0 + rr;
    int gc = x0 - 8 + 4 * c4;
    float4 v1 = make_float4(0.f, 0.f, 0.f, 0.f);
    float4 v2 = make_float4(0.f, 0.f, 0.f, 0.f);
    if ((unsigned)gr < (unsigned)IMG_H && (unsigned)gc < (unsigned)IMG_W) {
      int o = gr * IMG_W + gc;
      v1 = *(const float4*)(p1 + o);
      v2 = *(const float4*)(p2 + o);
    }
    int slot = mod24(gr + 56);            // == (gr+8) mod 24, gr >= -8
    float* p = sin_ + slot * SP + 4 * c4;
    *(float4*)(p)      = v1;
    *(float4*)(p + SB) = v2;
  }
}

// vertical pass, 2-row register blocking, 4 planes.
// SSIM algebra only needs sigma1_sq+sigma2_sq (both variances >=0, so the
// reference's abs() is a no-op) -> convolve {x, y, x^2+y^2, x*y}:
// -20% acc FMAs, -20% sv_ writes, -20% H reads vs 5 planes.
template<int K>
__device__ __forceinline__ void v_col2(const float (&wk)[K],
                                       const float* __restrict__ sin_,
                                       float* __restrict__ sv_,
                                       int yc, int t) {
  constexpr int HK = K / 2;
  const int rp = (t * 1821) >> 16;        // t / 36, valid t < 288
  const int cc = t - rp * 36;
  const int r0 = rp * 2;
  const int cb = 4 * cc;

  float acc[4][2][4];
  #pragma unroll
  for (int d = 0; d < 4; ++d)
    #pragma unroll
    for (int r = 0; r < 2; ++r)
      #pragma unroll
      for (int j = 0; j < 4; ++j) acc[d][r][j] = 0.f;

  // slot of first tap row (row yc+r0-HK): ((yc+r0-HK)+8) mod 24
  const int us = mod24(yc + r0 + (8 - HK));
  const float* pA = sin_ + us * SP + cb;
  const float* pB = pA - NRING * SP;

  #pragma unroll
  for (int i = 0; i <= K; ++i) {
    const float* row = (us + i < NRING) ? pA : pB;
    float4 A  = *(const float4*)(row + i * SP);
    float4 Bv = *(const float4*)(row + i * SP + SB);
    float x[4] = {A.x, A.y, A.z, A.w};
    float y[4] = {Bv.x, Bv.y, Bv.z, Bv.w};
    float pp[4], qq[4];
    #pragma unroll
    for (int j = 0; j < 4; ++j) {
      pp[j] = fmaf(x[j], x[j], y[j] * y[j]);   // x^2 + y^2
      qq[j] = x[j] * y[j];                     // x * y
    }
    if (i < K) {            // contributes to row r0 with weight wk[i]
      const float w = wk[i];
      #pragma unroll
      for (int j = 0; j < 4; ++j) {
        acc[0][0][j] = fmaf(w, x[j],  acc[0][0][j]);
        acc[1][0][j] = fmaf(w, y[j],  acc[1][0][j]);
        acc[2][0][j] = fmaf(w, pp[j], acc[2][0][j]);
        acc[3][0][j] = fmaf(w, qq[j], acc[3][0][j]);
      }
    }
    if (i > 0) {            // contributes to row r0+1 with weight wk[i-1]
      const float w = wk[i - 1];
      #pragma unroll
      for (int j = 0; j < 4; ++j) {
        acc[0][1][j] = fmaf(w, x[j],  acc[0][1][j]);
        acc[1][1][j] = fmaf(w, y[j],  acc[1][1][j]);
        acc[2][1][j] = fmaf(w, pp[j], acc[2][1][j]);
        acc[3][1][j] = fmaf(w, qq[j], acc[3][1][j]);
      }
    }
  }

  #pragma unroll
  for (int d = 0; d < 4; ++d) {
    #pragma unroll
    for (int r = 0; r < 2; ++r) {
      float* vb = sv_ + d * PS + (r0 + r) * SVP + cb;
      *(float4*)vb = make_float4(acc[d][r][0], acc[d][r][1],
                                 acc[d][r][2], acc[d][r][3]);
    }
  }
}

// horizontal pass + partial ssim for (row rr, 4-col group g), 4 planes.
template<int K>
__device__ __forceinline__ void h_col(const float (&wk)[K],
                                      const float* __restrict__ sv_,
                                      int rr, int g, float (&accs)[4]) {
  constexpr int OFF = 8 - K / 2;
  float conv[4][4];
  #pragma unroll
  for (int d = 0; d < 4; ++d) {
    const float* vb = sv_ + d * PS + rr * SVP + 4 * g;
    float win[20];
    if constexpr (K == 5) {
      #pragma unroll
      for (int q = 1; q < 4; ++q) {
        float4 t4 = *(const float4*)(vb + 4 * q);
        win[4*q+0] = t4.x; win[4*q+1] = t4.y; win[4*q+2] = t4.z; win[4*q+3] = t4.w;
      }
    } else {
      #pragma unroll
      for (int q = 0; q < 5; ++q) {
        float4 t4 = *(const float4*)(vb + 4 * q);
        win[4*q+0] = t4.x; win[4*q+1] = t4.y; win[4*q+2] = t4.z; win[4*q+3] = t4.w;
      }
    }
    #pragma unroll
    for (int j = 0; j < 4; ++j) {
      float s = 0.f;
      #pragma unroll
      for (int t = 0; t < K; ++t) s = fmaf(wk[t], win[j + t + OFF], s);
      conv[d][j] = s;
    }
  }
  #pragma unroll
  for (int j = 0; j < 4; ++j) {
    float mu1 = conv[0][j], mu2 = conv[1][j];
    float P = conv[2][j], Q = conv[3][j];
    float mu11 = mu1 * mu1, mu22 = mu2 * mu2, mu12 = mu1 * mu2;
    float sg12 = Q - mu12;                 // sigma12
    float sgS  = P - mu11 - mu22;          // sigma1_sq + sigma2_sq
    float num  = fmaf(2.f, mu12, C1F) * fmaf(2.f, sg12, C2F);
    float den  = (mu11 + mu22 + C1F) * (sgS + C2F);
    float ssim = __fdividef(num, den);
    accs[j] += fminf(1.f, fmaxf(-1.f, ssim));
  }
}

// ---------------------------------------------------------------------------
// main fused kernel: grid = 96 images * 8 row-strips * 4 col-blocks = 3072
// block = 256 threads; LDS = 28416 (input ring) + 19456 (4 V planes) = 47872 B
//   -> 3 blocks/CU (12 waves/CU); 6 barriers per 8-row step
// ---------------------------------------------------------------------------
__global__ __launch_bounds__(256, 3)
void mssim_kernel(const float* __restrict__ b1, const float* __restrict__ b2,
                  const float* __restrict__ ws, float* __restrict__ out) {
  __shared__ __attribute__((aligned(16))) float sin_[NRING * SP];
  __shared__ __attribute__((aligned(16))) float sv_[4 * PS];

  const int tid = threadIdx.x;
  const int bid = blockIdx.x;
  const int img = bid >> 5;
  const int rem = bid & 31;
  const int y0  = (rem >> 2) * (RS * NSTEP);
  const int x0  = (rem & 3) * WOUT;
  const float* p1 = b1 + img * (IMG_H * IMG_W);
  const float* p2 = b2 + img * (IMG_H * IMG_W);
  float*       po = out + img * (IMG_H * IMG_W);

  // weights -> SGPRs (single scalar operand per FMA)
  float w17[17], w11[11], w5[5];
  #pragma unroll
  for (int i = 0; i < 17; ++i) w17[i] = to_sgpr(ws[32 + i]);
  #pragma unroll
  for (int i = 0; i < 11; ++i) w11[i] = to_sgpr(ws[8 + i]);
  #pragma unroll
  for (int i = 0; i < 5;  ++i) w5[i]  = to_sgpr(ws[i]);

  // preload halo rows y0-8 .. y0+7
  stage_rows<16>(p1, p2, sin_, y0 - 8, x0, tid);

  const int hr = tid >> 5;            // H row within step (0..7)
  const int hg = tid & 31;            // H 4-col group (0..31)
  const bool vact = tid < 144;        // V tasks: 4 row-pairs x 36 col groups

  #pragma unroll 1
  for (int step = 0; step < NSTEP; ++step) {
    const int yc = y0 + step * RS;
    stage_rows<RS>(p1, p2, sin_, yc + 8, x0, tid);  // rows yc+8..yc+15
    __syncthreads();

    float accs[4] = {0.f, 0.f, 0.f, 0.f};

    if (vact) v_col2<17>(w17, sin_, sv_, yc, tid);
    __syncthreads();
    h_col<17>(w17, sv_, hr, hg, accs);
    __syncthreads();

    if (vact) v_col2<11>(w11, sin_, sv_, yc, tid);
    __syncthreads();
    h_col<11>(w11, sv_, hr, hg, accs);
    __syncthreads();

    if (vact) v_col2<5>(w5, sin_, sv_, yc, tid);
    __syncthreads();
    h_col<5>(w5, sv_, hr, hg, accs);
    // no barrier needed here: next writer of sv_ (V17) is after the next
    // top-of-loop sync; the sin_ slots staged next iteration (rows yc+16..23,
    // overwriting rows yc-8..yc-1) were last read by V5 of THIS step, which
    // completes at the post-V5 sync above.

    // out = 1 - ((sum_s (1-(clip_s+1)/2))/3 + 1)/2  ==  0.25 + sum(clip_s)/12
    float4 o = make_float4(0.25f + accs[0] * (1.f / 12.f),
                           0.25f + accs[1] * (1.f / 12.f),
                           0.25f + accs[2] * (1.f / 12.f),
                           0.25f + accs[3] * (1.f / 12.f));
    *(float4*)(po + (yc + hr) * IMG_W + x0 + 4 * hg) = o;
  }
}

extern "C" void kernel_launch(void* const* d_in, const int* in_sizes, int n_in,
                              void* d_out, int out_size, void* d_ws, size_t ws_size,
                              hipStream_t stream) {
  const float* b1 = (const float*)d_in[0];
  const float* b2 = (const float*)d_in[1];
  const float* g0 = (const float*)d_in[2];
  const float* g1 = (const float*)d_in[3];
  const float* g2 = (const float*)d_in[4];
  float* ws  = (float*)d_ws;
  float* out = (float*)d_out;

  prep_weights_kernel<<<1, 64, 0, stream>>>(g0, g1, g2, ws);
  mssim_kernel<<<3072, 256, 0, stream>>>(b1, b2, ws, out);
}

// Round 5
// 517.019 us; speedup vs baseline: 1.5148x; 1.0384x over previous
//
#include <hip/hip_runtime.h>

#define IMG_H 512
#define IMG_W 512
#define WOUT  128          // output cols per block
#define WV    144          // WOUT + 16 halo cols (valid data cols per row)
#define SP    296          // sin_ slot pitch (floats); 1184B, 2-slot stride = 16-bank shift
#define SB    148          // b2 plane offset within a slot (floats), 592B (16B aligned)
#define NRING 28           // circular input row slots (24 live + 4 stage-ahead)
#define RS    8            // rows per step
#define NSTEP 8            // steps per block (64-row strip)
#define SVP   152          // sv_ row pitch (floats); 608B, 2-row stride = 16-bank shift
#define PS    (RS * SVP)   // sv_ plane stride (floats) = 1216
#define C1F   1.0e-4f
#define C2F   9.0e-4f

// ---------------------------------------------------------------------------
// prep: extract exact separable 1D weights from the 2D filters.
// ws layout (floats): [0..4]=w5, [8..18]=w11, [32..48]=w17
// ---------------------------------------------------------------------------
__global__ void prep_weights_kernel(const float* __restrict__ g0,
                                    const float* __restrict__ g1,
                                    const float* __restrict__ g2,
                                    float* __restrict__ ws) {
  if (blockIdx.x == 0 && threadIdx.x == 0) {
    const float* gs[3] = {g0, g1, g2};
    const int ks[3]  = {5, 11, 17};
    const int off[3] = {0, 8, 32};
    for (int s = 0; s < 3; ++s) {
      const float* g = gs[s];
      int k = ks[s], h = k / 2;
      double rs = 1.0 / sqrt((double)g[h * k + h]);
      for (int j = 0; j < k; ++j)
        ws[off[s] + j] = (float)((double)g[h * k + j] * rs);
    }
  }
}

__device__ __forceinline__ float to_sgpr(float x) {
  int i = __builtin_amdgcn_readfirstlane(__builtin_bit_cast(int, x));
  return __builtin_bit_cast(float, i);
}

__device__ __forceinline__ int mod28(int x) {  // valid for 0 <= x < ~1000
  return x - 28 * ((x * 9363) >> 18);
}

// slot(row gr) = (gr + 12) mod 28; the ring holds 28 consecutive rows.

// prologue staging, float4 granularity, all 256 threads:
// rows gr0..gr0+NROWS-1. Magic t/36 valid for t < 864 (NROWS<=24).
template<int NROWS>
__device__ __forceinline__ void stage_rows(const float* __restrict__ p1,
                                           const float* __restrict__ p2,
                                           float* __restrict__ sin_,
                                           int gr0, int x0, int tid) {
  constexpr int NT = NROWS * 36;
  for (int t = tid; t < NT; t += 256) {
    int rr = (t * 1821) >> 16;            // t / 36
    int c4 = t - rr * 36;
    int gr = gr0 + rr;
    int gc = x0 - 8 + 4 * c4;
    float4 v1 = make_float4(0.f, 0.f, 0.f, 0.f);
    float4 v2 = make_float4(0.f, 0.f, 0.f, 0.f);
    if ((unsigned)gr < (unsigned)IMG_H && (unsigned)gc < (unsigned)IMG_W) {
      int o = gr * IMG_W + gc;
      v1 = *(const float4*)(p1 + o);
      v2 = *(const float4*)(p2 + o);
    }
    int slot = mod28(gr + 12 + 28);       // gr >= -8 in prologue
    float* p = sin_ + slot * SP + 4 * c4;
    *(float4*)(p)      = v1;
    *(float4*)(p + SB) = v2;
  }
}

// in-loop staging executed by wave 3 (64 threads) DURING the V phases.
// NR rows starting at gr0 (gr0 >= 16 always, no +28 bias needed).
template<int NR>
__device__ __forceinline__ void stage_span(const float* __restrict__ p1,
                                           const float* __restrict__ p2,
                                           float* __restrict__ sin_,
                                           int gr0, int x0, int st) {
  constexpr int NT = NR * 36;
  for (int t = st; t < NT; t += 64) {
    int rr = (t * 1821) >> 16;            // t / 36
    int c4 = t - rr * 36;
    int gr = gr0 + rr;
    int gc = x0 - 8 + 4 * c4;
    float4 v1 = make_float4(0.f, 0.f, 0.f, 0.f);
    float4 v2 = make_float4(0.f, 0.f, 0.f, 0.f);
    if ((unsigned)gr < (unsigned)IMG_H && (unsigned)gc < (unsigned)IMG_W) {
      int o = gr * IMG_W + gc;
      v1 = *(const float4*)(p1 + o);
      v2 = *(const float4*)(p2 + o);
    }
    int slot = mod28(gr + 12);
    float* p = sin_ + slot * SP + 4 * c4;
    *(float4*)(p)      = v1;
    *(float4*)(p + SB) = v2;
  }
}

// vertical pass, 2-row register blocking, 4 planes.
// SSIM algebra only needs sigma1_sq+sigma2_sq (both variances >=0, so the
// reference's abs() is a no-op) -> convolve {x, y, x^2+y^2, x*y}.
template<int K>
__device__ __forceinline__ void v_col2(const float (&wk)[K],
                                       const float* __restrict__ sin_,
                                       float* __restrict__ sv_,
                                       int yc, int t) {
  constexpr int HK = K / 2;
  const int rp = (t * 1821) >> 16;        // t / 36, valid t < 288
  const int cc = t - rp * 36;
  const int r0 = rp * 2;
  const int cb = 4 * cc;

  float acc[4][2][4];
  #pragma unroll
  for (int d = 0; d < 4; ++d)
    #pragma unroll
    for (int r = 0; r < 2; ++r)
      #pragma unroll
      for (int j = 0; j < 4; ++j) acc[d][r][j] = 0.f;

  // slot of first tap row (row yc+r0-HK): (yc+r0-HK+12) mod 28
  const int us = mod28(yc + r0 + (12 - HK));
  const float* pA = sin_ + us * SP + cb;
  const float* pB = pA - NRING * SP;

  #pragma unroll
  for (int i = 0; i <= K; ++i) {
    const float* row = (us + i < NRING) ? pA : pB;
    float4 A  = *(const float4*)(row + i * SP);
    float4 Bv = *(const float4*)(row + i * SP + SB);
    float x[4] = {A.x, A.y, A.z, A.w};
    float y[4] = {Bv.x, Bv.y, Bv.z, Bv.w};
    float pp[4], qq[4];
    #pragma unroll
    for (int j = 0; j < 4; ++j) {
      pp[j] = fmaf(x[j], x[j], y[j] * y[j]);   // x^2 + y^2
      qq[j] = x[j] * y[j];                     // x * y
    }
    if (i < K) {            // contributes to row r0 with weight wk[i]
      const float w = wk[i];
      #pragma unroll
      for (int j = 0; j < 4; ++j) {
        acc[0][0][j] = fmaf(w, x[j],  acc[0][0][j]);
        acc[1][0][j] = fmaf(w, y[j],  acc[1][0][j]);
        acc[2][0][j] = fmaf(w, pp[j], acc[2][0][j]);
        acc[3][0][j] = fmaf(w, qq[j], acc[3][0][j]);
      }
    }
    if (i > 0) {            // contributes to row r0+1 with weight wk[i-1]
      const float w = wk[i - 1];
      #pragma unroll
      for (int j = 0; j < 4; ++j) {
        acc[0][1][j] = fmaf(w, x[j],  acc[0][1][j]);
        acc[1][1][j] = fmaf(w, y[j],  acc[1][1][j]);
        acc[2][1][j] = fmaf(w, pp[j], acc[2][1][j]);
        acc[3][1][j] = fmaf(w, qq[j], acc[3][1][j]);
      }
    }
  }

  #pragma unroll
  for (int d = 0; d < 4; ++d) {
    #pragma unroll
    for (int r = 0; r < 2; ++r) {
      float* vb = sv_ + d * PS + (r0 + r) * SVP + cb;
      *(float4*)vb = make_float4(acc[d][r][0], acc[d][r][1],
                                 acc[d][r][2], acc[d][r][3]);
    }
  }
}

// horizontal pass + partial ssim for (row rr, 4-col group g), 4 planes.
template<int K>
__device__ __forceinline__ void h_col(const float (&wk)[K],
                                      const float* __restrict__ sv_,
                                      int rr, int g, float (&accs)[4]) {
  constexpr int OFF = 8 - K / 2;
  float conv[4][4];
  #pragma unroll
  for (int d = 0; d < 4; ++d) {
    const float* vb = sv_ + d * PS + rr * SVP + 4 * g;
    float win[20];
    if constexpr (K == 5) {
      #pragma unroll
      for (int q = 1; q < 4; ++q) {
        float4 t4 = *(const float4*)(vb + 4 * q);
        win[4*q+0] = t4.x; win[4*q+1] = t4.y; win[4*q+2] = t4.z; win[4*q+3] = t4.w;
      }
    } else {
      #pragma unroll
      for (int q = 0; q < 5; ++q) {
        float4 t4 = *(const float4*)(vb + 4 * q);
        win[4*q+0] = t4.x; win[4*q+1] = t4.y; win[4*q+2] = t4.z; win[4*q+3] = t4.w;
      }
    }
    #pragma unroll
    for (int j = 0; j < 4; ++j) {
      float s = 0.f;
      #pragma unroll
      for (int t = 0; t < K; ++t) s = fmaf(wk[t], win[j + t + OFF], s);
      conv[d][j] = s;
    }
  }
  #pragma unroll
  for (int j = 0; j < 4; ++j) {
    float mu1 = conv[0][j], mu2 = conv[1][j];
    float P = conv[2][j], Q = conv[3][j];
    float mu11 = mu1 * mu1, mu22 = mu2 * mu2, mu12 = mu1 * mu2;
    float sg12 = Q - mu12;                 // sigma12
    float sgS  = P - mu11 - mu22;          // sigma1_sq + sigma2_sq
    float num  = fmaf(2.f, mu12, C1F) * fmaf(2.f, sg12, C2F);
    float den  = (mu11 + mu22 + C1F) * (sgS + C2F);
    float ssim = __fdividef(num, den);
    accs[j] += fminf(1.f, fmaxf(-1.f, ssim));
  }
}

// ---------------------------------------------------------------------------
// main fused kernel: grid = 96 images * 8 row-strips * 4 col-blocks = 3072
// block = 256 threads; LDS = 33152 (28-slot ring) + 19456 (4 V planes) = 52608
//   -> 3 blocks/CU (12 waves/CU); 6 barriers per 8-row step.
// Staging of next-step rows runs on wave 3 DURING the V phases (which only
// use threads 0..143), using the 4 spare ring slots. Safety per phase:
//   stage-a rows yc+16..19 overwrite slots of yc-12..-9 (V17 reads >= yc-8)
//   stage-b rows yc+20..22 overwrite slots of yc-8 ..-6 (V11 reads >= yc-5)
//   stage-c row  yc+23     overwrites slot  of yc-5     (V5  reads >= yc-2)
// Last step stages nothing (its stage-a would clobber rows V17 still reads).
// ---------------------------------------------------------------------------
__global__ __launch_bounds__(256, 3)
void mssim_kernel(const float* __restrict__ b1, const float* __restrict__ b2,
                  const float* __restrict__ ws, float* __restrict__ out) {
  __shared__ __attribute__((aligned(16))) float sin_[NRING * SP];
  __shared__ __attribute__((aligned(16))) float sv_[4 * PS];

  const int tid = threadIdx.x;
  const int bid = blockIdx.x;
  const int img = bid >> 5;
  const int rem = bid & 31;
  const int y0  = (rem >> 2) * (RS * NSTEP);
  const int x0  = (rem & 3) * WOUT;
  const float* p1 = b1 + img * (IMG_H * IMG_W);
  const float* p2 = b2 + img * (IMG_H * IMG_W);
  float*       po = out + img * (IMG_H * IMG_W);

  // weights -> SGPRs (single scalar operand per FMA)
  float w17[17], w11[11], w5[5];
  #pragma unroll
  for (int i = 0; i < 17; ++i) w17[i] = to_sgpr(ws[32 + i]);
  #pragma unroll
  for (int i = 0; i < 11; ++i) w11[i] = to_sgpr(ws[8 + i]);
  #pragma unroll
  for (int i = 0; i < 5;  ++i) w5[i]  = to_sgpr(ws[i]);

  // prologue: stage rows y0-8 .. y0+15 (everything step 0's V passes read)
  stage_rows<24>(p1, p2, sin_, y0 - 8, x0, tid);

  const int hr = tid >> 5;            // H row within step (0..7)
  const int hg = tid & 31;            // H 4-col group (0..31)
  const bool vact = tid < 144;        // V tasks: 4 row-pairs x 36 col groups
  const int  st   = tid - 192;        // stage lane (wave 3), >=0 for tid>=192

  #pragma unroll 1
  for (int step = 0; step < NSTEP; ++step) {
    const int yc = y0 + step * RS;
    const bool do_stage = (st >= 0) && (step < NSTEP - 1);
    __syncthreads();   // prologue / prev-step stage-c + H5 sv_ reads done

    float accs[4] = {0.f, 0.f, 0.f, 0.f};

    if (vact) v_col2<17>(w17, sin_, sv_, yc, tid);
    else if (do_stage) stage_span<4>(p1, p2, sin_, yc + 16, x0, st);
    __syncthreads();
    h_col<17>(w17, sv_, hr, hg, accs);
    __syncthreads();

    if (vact) v_col2<11>(w11, sin_, sv_, yc, tid);
    else if (do_stage) stage_span<3>(p1, p2, sin_, yc + 20, x0, st);
    __syncthreads();
    h_col<11>(w11, sv_, hr, hg, accs);
    __syncthreads();

    if (vact) v_col2<5>(w5, sin_, sv_, yc, tid);
    else if (do_stage) stage_span<1>(p1, p2, sin_, yc + 23, x0, st);
    __syncthreads();
    h_col<5>(w5, sv_, hr, hg, accs);

    // out = 1 - ((sum_s (1-(clip_s+1)/2))/3 + 1)/2  ==  0.25 + sum(clip_s)/12
    float4 o = make_float4(0.25f + accs[0] * (1.f / 12.f),
                           0.25f + accs[1] * (1.f / 12.f),
                           0.25f + accs[2] * (1.f / 12.f),
                           0.25f + accs[3] * (1.f / 12.f));
    *(float4*)(po + (yc + hr) * IMG_W + x0 + 4 * hg) = o;
  }
}

extern "C" void kernel_launch(void* const* d_in, const int* in_sizes, int n_in,
                              void* d_out, int out_size, void* d_ws, size_t ws_size,
                              hipStream_t stream) {
  const float* b1 = (const float*)d_in[0];
  const float* b2 = (const float*)d_in[1];
  const float* g0 = (const float*)d_in[2];
  const float* g1 = (const float*)d_in[3];
  const float* g2 = (const float*)d_in[4];
  float* ws  = (float*)d_ws;
  float* out = (float*)d_out;

  prep_weights_kernel<<<1, 64, 0, stream>>>(g0, g1, g2, ws);
  mssim_kernel<<<3072, 256, 0, stream>>>(b1, b2, ws, out);
}

// Round 6
// 514.951 us; speedup vs baseline: 1.5208x; 1.0040x over previous
//
#include <hip/hip_runtime.h>

#define IMG_H 512
#define IMG_W 512
#define WOUT  128          // output cols per block
#define WV    144          // WOUT + 16 halo cols (valid data cols per row)
#define SP    296          // sin_ slot pitch (floats); 1184B, 2-slot stride = 16-bank shift
#define SB    148          // b2 plane offset within a slot (floats), 592B (16B aligned)
#define NRING 28           // circular input row slots (24 live + 4 stage-ahead)
#define RS    8            // rows per step
#define NSTEP 8            // steps per block (64-row strip)
#define SVP   152          // sv_ row pitch (floats); 608B, 2-row stride = 16-bank shift
#define PS    (RS * SVP)   // sv_ plane stride (floats) = 1216
#define C1F   1.0e-4f
#define C2F   9.0e-4f

// ---------------------------------------------------------------------------
// prep: extract exact separable 1D weights from the 2D filters.
// ws layout (floats): [0..4]=w5, [8..18]=w11, [32..48]=w17
// ---------------------------------------------------------------------------
__global__ void prep_weights_kernel(const float* __restrict__ g0,
                                    const float* __restrict__ g1,
                                    const float* __restrict__ g2,
                                    float* __restrict__ ws) {
  if (blockIdx.x == 0 && threadIdx.x == 0) {
    const float* gs[3] = {g0, g1, g2};
    const int ks[3]  = {5, 11, 17};
    const int off[3] = {0, 8, 32};
    for (int s = 0; s < 3; ++s) {
      const float* g = gs[s];
      int k = ks[s], h = k / 2;
      double rs = 1.0 / sqrt((double)g[h * k + h]);
      for (int j = 0; j < k; ++j)
        ws[off[s] + j] = (float)((double)g[h * k + j] * rs);
    }
  }
}

__device__ __forceinline__ float to_sgpr(float x) {
  int i = __builtin_amdgcn_readfirstlane(__builtin_bit_cast(int, x));
  return __builtin_bit_cast(float, i);
}

__device__ __forceinline__ int mod28(int x) {  // valid for 0 <= x < ~1000
  return x - 28 * ((x * 9363) >> 18);
}

// slot(row gr) = (gr + 12) mod 28; the ring holds 28 consecutive rows.

// prologue staging, float4 granularity, all 256 threads:
// rows gr0..gr0+NROWS-1. Magic t/36 valid for t < 864 (NROWS<=24).
template<int NROWS>
__device__ __forceinline__ void stage_rows(const float* __restrict__ p1,
                                           const float* __restrict__ p2,
                                           float* __restrict__ sin_,
                                           int gr0, int x0, int tid) {
  constexpr int NT = NROWS * 36;
  for (int t = tid; t < NT; t += 256) {
    int rr = (t * 1821) >> 16;            // t / 36
    int c4 = t - rr * 36;
    int gr = gr0 + rr;
    int gc = x0 - 8 + 4 * c4;
    float4 v1 = make_float4(0.f, 0.f, 0.f, 0.f);
    float4 v2 = make_float4(0.f, 0.f, 0.f, 0.f);
    if ((unsigned)gr < (unsigned)IMG_H && (unsigned)gc < (unsigned)IMG_W) {
      int o = gr * IMG_W + gc;
      v1 = *(const float4*)(p1 + o);
      v2 = *(const float4*)(p2 + o);
    }
    int slot = mod28(gr + 12 + 28);       // gr >= -8 in prologue
    float* p = sin_ + slot * SP + 4 * c4;
    *(float4*)(p)      = v1;
    *(float4*)(p + SB) = v2;
  }
}

// in-loop staging executed by wave 3 (64 threads) DURING the V phases.
// NR rows starting at gr0 (gr0 >= 16 always, no +28 bias needed).
template<int NR>
__device__ __forceinline__ void stage_span(const float* __restrict__ p1,
                                           const float* __restrict__ p2,
                                           float* __restrict__ sin_,
                                           int gr0, int x0, int st) {
  constexpr int NT = NR * 36;
  for (int t = st; t < NT; t += 64) {
    int rr = (t * 1821) >> 16;            // t / 36
    int c4 = t - rr * 36;
    int gr = gr0 + rr;
    int gc = x0 - 8 + 4 * c4;
    float4 v1 = make_float4(0.f, 0.f, 0.f, 0.f);
    float4 v2 = make_float4(0.f, 0.f, 0.f, 0.f);
    if ((unsigned)gr < (unsigned)IMG_H && (unsigned)gc < (unsigned)IMG_W) {
      int o = gr * IMG_W + gc;
      v1 = *(const float4*)(p1 + o);
      v2 = *(const float4*)(p2 + o);
    }
    int slot = mod28(gr + 12);
    float* p = sin_ + slot * SP + 4 * c4;
    *(float4*)(p)      = v1;
    *(float4*)(p + SB) = v2;
  }
}

// vertical pass, 2-row register blocking, 4 planes, 1-tap software pipeline.
// SSIM algebra only needs sigma1_sq+sigma2_sq (both variances >=0, so the
// reference's abs() is a no-op) -> convolve {x, y, x^2+y^2, x*y}.
// The tap loop prefetches tap i+1's x/y float4s BEFORE tap i's ~44 dependent
// VALU ops, giving the scheduler an explicit load-ahead window to hide the
// ~120-cycle LDS latency (kernel is latency-bound: per-SIMD issue ~27%).
template<int K>
__device__ __forceinline__ void v_col2(const float (&wk)[K],
                                       const float* __restrict__ sin_,
                                       float* __restrict__ sv_,
                                       int yc, int t) {
  constexpr int HK = K / 2;
  const int rp = (t * 1821) >> 16;        // t / 36, valid t < 288
  const int cc = t - rp * 36;
  const int r0 = rp * 2;
  const int cb = 4 * cc;

  float acc[4][2][4];
  #pragma unroll
  for (int d = 0; d < 4; ++d)
    #pragma unroll
    for (int r = 0; r < 2; ++r)
      #pragma unroll
      for (int j = 0; j < 4; ++j) acc[d][r][j] = 0.f;

  // slot of first tap row (row yc+r0-HK): (yc+r0-HK+12) mod 28
  const int us = mod28(yc + r0 + (12 - HK));
  const float* pA = sin_ + us * SP + cb;
  const float* pB = pA - NRING * SP;

  // prefetch tap 0 (us < NRING always, so base is pA)
  float4 X = *(const float4*)(pA);
  float4 Y = *(const float4*)(pA + SB);

  #pragma unroll
  for (int i = 0; i <= K; ++i) {
    float4 Xc = X, Yc = Y;
    if (i < K) {                          // prefetch tap i+1
      const float* rn = (us + i + 1 < NRING) ? pA : pB;
      X = *(const float4*)(rn + (i + 1) * SP);
      Y = *(const float4*)(rn + (i + 1) * SP + SB);
    }
    float x[4] = {Xc.x, Xc.y, Xc.z, Xc.w};
    float y[4] = {Yc.x, Yc.y, Yc.z, Yc.w};
    float pp[4], qq[4];
    #pragma unroll
    for (int j = 0; j < 4; ++j) {
      pp[j] = fmaf(x[j], x[j], y[j] * y[j]);   // x^2 + y^2
      qq[j] = x[j] * y[j];                     // x * y
    }
    if (i < K) {            // contributes to row r0 with weight wk[i]
      const float w = wk[i];
      #pragma unroll
      for (int j = 0; j < 4; ++j) {
        acc[0][0][j] = fmaf(w, x[j],  acc[0][0][j]);
        acc[1][0][j] = fmaf(w, y[j],  acc[1][0][j]);
        acc[2][0][j] = fmaf(w, pp[j], acc[2][0][j]);
        acc[3][0][j] = fmaf(w, qq[j], acc[3][0][j]);
      }
    }
    if (i > 0) {            // contributes to row r0+1 with weight wk[i-1]
      const float w = wk[i - 1];
      #pragma unroll
      for (int j = 0; j < 4; ++j) {
        acc[0][1][j] = fmaf(w, x[j],  acc[0][1][j]);
        acc[1][1][j] = fmaf(w, y[j],  acc[1][1][j]);
        acc[2][1][j] = fmaf(w, pp[j], acc[2][1][j]);
        acc[3][1][j] = fmaf(w, qq[j], acc[3][1][j]);
      }
    }
  }

  #pragma unroll
  for (int d = 0; d < 4; ++d) {
    #pragma unroll
    for (int r = 0; r < 2; ++r) {
      float* vb = sv_ + d * PS + (r0 + r) * SVP + cb;
      *(float4*)vb = make_float4(acc[d][r][0], acc[d][r][1],
                                 acc[d][r][2], acc[d][r][3]);
    }
  }
}

// horizontal pass + partial ssim for (row rr, 4-col group g), 4 planes.
template<int K>
__device__ __forceinline__ void h_col(const float (&wk)[K],
                                      const float* __restrict__ sv_,
                                      int rr, int g, float (&accs)[4]) {
  constexpr int OFF = 8 - K / 2;
  float conv[4][4];
  #pragma unroll
  for (int d = 0; d < 4; ++d) {
    const float* vb = sv_ + d * PS + rr * SVP + 4 * g;
    float win[20];
    if constexpr (K == 5) {
      #pragma unroll
      for (int q = 1; q < 4; ++q) {
        float4 t4 = *(const float4*)(vb + 4 * q);
        win[4*q+0] = t4.x; win[4*q+1] = t4.y; win[4*q+2] = t4.z; win[4*q+3] = t4.w;
      }
    } else {
      #pragma unroll
      for (int q = 0; q < 5; ++q) {
        float4 t4 = *(const float4*)(vb + 4 * q);
        win[4*q+0] = t4.x; win[4*q+1] = t4.y; win[4*q+2] = t4.z; win[4*q+3] = t4.w;
      }
    }
    #pragma unroll
    for (int j = 0; j < 4; ++j) {
      float s = 0.f;
      #pragma unroll
      for (int t = 0; t < K; ++t) s = fmaf(wk[t], win[j + t + OFF], s);
      conv[d][j] = s;
    }
  }
  #pragma unroll
  for (int j = 0; j < 4; ++j) {
    float mu1 = conv[0][j], mu2 = conv[1][j];
    float P = conv[2][j], Q = conv[3][j];
    float mu11 = mu1 * mu1, mu22 = mu2 * mu2, mu12 = mu1 * mu2;
    float sg12 = Q - mu12;                 // sigma12
    float sgS  = P - mu11 - mu22;          // sigma1_sq + sigma2_sq
    float num  = fmaf(2.f, mu12, C1F) * fmaf(2.f, sg12, C2F);
    float den  = (mu11 + mu22 + C1F) * (sgS + C2F);
    float ssim = __fdividef(num, den);
    accs[j] += fminf(1.f, fmaxf(-1.f, ssim));
  }
}

// ---------------------------------------------------------------------------
// main fused kernel: grid = 96 images * 8 row-strips * 4 col-blocks = 3072
// block = 256 threads; LDS = 33152 (28-slot ring) + 19456 (4 V planes) = 52608
//   -> 3 blocks/CU (12 waves/CU); 6 barriers per 8-row step.
// Staging of next-step rows runs on wave 3 DURING the V phases (which only
// use threads 0..143), using the 4 spare ring slots. Safety per phase:
//   stage-a rows yc+16..19 overwrite slots of yc-12..-9 (V17 reads >= yc-8)
//   stage-b rows yc+20..22 overwrite slots of yc-8 ..-6 (V11 reads >= yc-5)
//   stage-c row  yc+23     overwrites slot  of yc-5     (V5  reads >= yc-2)
// Last step stages nothing (its stage-a would clobber rows V17 still reads).
// s_setprio(1) around the V body: V phases have wave role-diversity (V waves
// vs stage wave vs other blocks' H waves) and V is the per-block critical
// path -> bias CU issue arbitration toward V waves (T5-positive regime).
// ---------------------------------------------------------------------------
__global__ __launch_bounds__(256, 3)
void mssim_kernel(const float* __restrict__ b1, const float* __restrict__ b2,
                  const float* __restrict__ ws, float* __restrict__ out) {
  __shared__ __attribute__((aligned(16))) float sin_[NRING * SP];
  __shared__ __attribute__((aligned(16))) float sv_[4 * PS];

  const int tid = threadIdx.x;
  const int bid = blockIdx.x;
  const int img = bid >> 5;
  const int rem = bid & 31;
  const int y0  = (rem >> 2) * (RS * NSTEP);
  const int x0  = (rem & 3) * WOUT;
  const float* p1 = b1 + img * (IMG_H * IMG_W);
  const float* p2 = b2 + img * (IMG_H * IMG_W);
  float*       po = out + img * (IMG_H * IMG_W);

  // weights -> SGPRs (single scalar operand per FMA)
  float w17[17], w11[11], w5[5];
  #pragma unroll
  for (int i = 0; i < 17; ++i) w17[i] = to_sgpr(ws[32 + i]);
  #pragma unroll
  for (int i = 0; i < 11; ++i) w11[i] = to_sgpr(ws[8 + i]);
  #pragma unroll
  for (int i = 0; i < 5;  ++i) w5[i]  = to_sgpr(ws[i]);

  // prologue: stage rows y0-8 .. y0+15 (everything step 0's V passes read)
  stage_rows<24>(p1, p2, sin_, y0 - 8, x0, tid);

  const int hr = tid >> 5;            // H row within step (0..7)
  const int hg = tid & 31;            // H 4-col group (0..31)
  const bool vact = tid < 144;        // V tasks: 4 row-pairs x 36 col groups
  const int  st   = tid - 192;        // stage lane (wave 3), >=0 for tid>=192

  #pragma unroll 1
  for (int step = 0; step < NSTEP; ++step) {
    const int yc = y0 + step * RS;
    const bool do_stage = (st >= 0) && (step < NSTEP - 1);
    __syncthreads();   // prologue / prev-step stage-c + H5 sv_ reads done

    float accs[4] = {0.f, 0.f, 0.f, 0.f};

    if (vact) {
      __builtin_amdgcn_s_setprio(1);
      v_col2<17>(w17, sin_, sv_, yc, tid);
      __builtin_amdgcn_s_setprio(0);
    } else if (do_stage) stage_span<4>(p1, p2, sin_, yc + 16, x0, st);
    __syncthreads();
    h_col<17>(w17, sv_, hr, hg, accs);
    __syncthreads();

    if (vact) {
      __builtin_amdgcn_s_setprio(1);
      v_col2<11>(w11, sin_, sv_, yc, tid);
      __builtin_amdgcn_s_setprio(0);
    } else if (do_stage) stage_span<3>(p1, p2, sin_, yc + 20, x0, st);
    __syncthreads();
    h_col<11>(w11, sv_, hr, hg, accs);
    __syncthreads();

    if (vact) {
      __builtin_amdgcn_s_setprio(1);
      v_col2<5>(w5, sin_, sv_, yc, tid);
      __builtin_amdgcn_s_setprio(0);
    } else if (do_stage) stage_span<1>(p1, p2, sin_, yc + 23, x0, st);
    __syncthreads();
    h_col<5>(w5, sv_, hr, hg, accs);

    // out = 1 - ((sum_s (1-(clip_s+1)/2))/3 + 1)/2  ==  0.25 + sum(clip_s)/12
    float4 o = make_float4(0.25f + accs[0] * (1.f / 12.f),
                           0.25f + accs[1] * (1.f / 12.f),
                           0.25f + accs[2] * (1.f / 12.f),
                           0.25f + accs[3] * (1.f / 12.f));
    *(float4*)(po + (yc + hr) * IMG_W + x0 + 4 * hg) = o;
  }
}

extern "C" void kernel_launch(void* const* d_in, const int* in_sizes, int n_in,
                              void* d_out, int out_size, void* d_ws, size_t ws_size,
                              hipStream_t stream) {
  const float* b1 = (const float*)d_in[0];
  const float* b2 = (const float*)d_in[1];
  const float* g0 = (const float*)d_in[2];
  const float* g1 = (const float*)d_in[3];
  const float* g2 = (const float*)d_in[4];
  float* ws  = (float*)d_ws;
  float* out = (float*)d_out;

  prep_weights_kernel<<<1, 64, 0, stream>>>(g0, g1, g2, ws);
  mssim_kernel<<<3072, 256, 0, stream>>>(b1, b2, ws, out);
}